// Round 4
// baseline (638.143 us; speedup 1.0000x reference)
//
#include <hip/hip_runtime.h>
#include <hip/hip_bf16.h>

// MHA forward: x[4,2048,1024] -> qkv GEMM -> flash attention (transposed
// S^T/O^T, LDS-free, barrier-free: all MFMA operands loaded directly from
// global in fragment layout; P in registers; l via ones-row MFMA)
// -> out proj. bf16 MFMA 16x16x32, fp32 accumulate.

typedef __attribute__((ext_vector_type(8))) short short8;
typedef __attribute__((ext_vector_type(4))) float f32x4;

#define GLD16(g, l)                                                            \
  __builtin_amdgcn_global_load_lds(                                            \
      (const __attribute__((address_space(1))) unsigned int*)(g),              \
      (__attribute__((address_space(3))) unsigned int*)(l), 16, 0, 0)

#define SCL2E 0.1803368801111204f /* 0.125 * log2(e), folded into W_q */
#define L2E 1.44269504088896340736f

__device__ __forceinline__ unsigned short f2b(float f) {
  union { float f; unsigned int u; } v; v.f = f;
  unsigned int u = v.u;
  return (unsigned short)((u + 0x7fffu + ((u >> 16) & 1u)) >> 16);
}
__device__ __forceinline__ unsigned int fbits(float f) {
  union { float f; unsigned int u; } v; v.f = f; return v.u;
}

// ---------------- elementwise fp32 -> bf16 ----------------
__global__ void cvt_bf16(const float* __restrict__ in, ushort* __restrict__ out, int n) {
  int i = (blockIdx.x * blockDim.x + threadIdx.x) * 4;
  if (i + 3 < n) {
    float4 f = *(const float4*)(in + i);
    ushort4 o;
    o.x = f2b(f.x); o.y = f2b(f.y); o.z = f2b(f.z); o.w = f2b(f.w);
    *(ushort4*)(out + i) = o;
  }
}

// ---------------- bias, q-part scaled by 0.125*log2e ----------------
__global__ void scale_bias_q(const float* __restrict__ b, float* __restrict__ out, int n) {
  int i = blockIdx.x * blockDim.x + threadIdx.x;
  if (i < n) out[i] = b[i] * (((i % 192) < 64) ? SCL2E : 1.0f);
}

// -------- W[K][N] fp32 -> Wt[N][K] bf16; QSCALE: scale q-cols --------
template <int QSCALE>
__global__ void transpose_cvt(const float* __restrict__ W, ushort* __restrict__ Wt,
                              int K, int N) {
  __shared__ float tile[64][65];
  int n0 = blockIdx.x * 64, k0 = blockIdx.y * 64;
  int tx = threadIdx.x & 63, ty = threadIdx.x >> 6;
#pragma unroll
  for (int i = 0; i < 64; i += 4)
    tile[ty + i][tx] = W[(size_t)(k0 + ty + i) * N + n0 + tx];
  __syncthreads();
#pragma unroll
  for (int i = 0; i < 64; i += 4) {
    int n = n0 + ty + i;
    float s = (QSCALE && ((n % 192) < 64)) ? SCL2E : 1.0f;
    Wt[(size_t)n * K + k0 + tx] = f2b(tile[tx][ty + i] * s);
  }
}

// ---------------- GEMM: C[M,N] = A[M,K] @ Bt[N,K]^T + bias ----------------
template <int OUTF32>
__global__ __launch_bounds__(256, 2) void gemm_bt_bias(
    const ushort* __restrict__ A, const ushort* __restrict__ Bt,
    const float* __restrict__ bias, void* __restrict__ Cout,
    int M, int N, int K) {
  __shared__ ushort As[128 * 64];
  __shared__ ushort Bs[128 * 64];
  const int lane = threadIdx.x & 63;
  const int wv = threadIdx.x >> 6;
  const int bm = blockIdx.y, bn = blockIdx.x;
  const int wm = wv >> 1, wn = wv & 1;
  f32x4 acc[4][4] = {};
  const size_t arow0 = (size_t)bm * 128;
  const size_t brow0 = (size_t)bn * 128;

  for (int k0 = 0; k0 < K; k0 += 64) {
    __syncthreads();
#pragma unroll
    for (int i = 0; i < 4; ++i) {
      int r = wv * 32 + i * 8 + (lane >> 3);
      const ushort* ga = A + (arow0 + r) * K + k0 + (lane & 7) * 8;
      GLD16(ga, As + (wv * 32 + i * 8) * 64);
      const ushort* gb = Bt + (brow0 + r) * K + k0 + (lane & 7) * 8;
      GLD16(gb, Bs + (wv * 32 + i * 8) * 64);
    }
    __syncthreads();
    short8 af[2][4], bf[2][4];
#pragma unroll
    for (int kf = 0; kf < 2; ++kf)
#pragma unroll
      for (int t = 0; t < 4; ++t) {
        af[kf][t] = *(const short8*)(As + (wm * 64 + t * 16 + (lane & 15)) * 64 +
                                     kf * 32 + (lane >> 4) * 8);
        bf[kf][t] = *(const short8*)(Bs + (wn * 64 + t * 16 + (lane & 15)) * 64 +
                                     kf * 32 + (lane >> 4) * 8);
      }
#pragma unroll
    for (int kf = 0; kf < 2; ++kf)
#pragma unroll
      for (int mt = 0; mt < 4; ++mt)
#pragma unroll
        for (int nt = 0; nt < 4; ++nt)
          acc[mt][nt] = __builtin_amdgcn_mfma_f32_16x16x32_bf16(
              af[kf][mt], bf[kf][nt], acc[mt][nt], 0, 0, 0);
  }
#pragma unroll
  for (int nt = 0; nt < 4; ++nt) {
    int col = bn * 128 + wn * 64 + nt * 16 + (lane & 15);
    float bv = bias[col];
#pragma unroll
    for (int mt = 0; mt < 4; ++mt) {
      int row0 = bm * 128 + wm * 64 + mt * 16 + (lane >> 4) * 4;
#pragma unroll
      for (int r = 0; r < 4; ++r) {
        float v = acc[mt][nt][r] + bv;
        if (OUTF32)
          ((float*)Cout)[(size_t)(row0 + r) * N + col] = v;
        else
          ((ushort*)Cout)[(size_t)(row0 + r) * N + col] = f2b(v);
      }
    }
  }
}

// ------- V^T extraction: qkv -> vtg[bh][64 d][2048 keys], key order
// permuted within each 32-key chunk so flash PV A-frags are contiguous:
// position p=8g+j holds key sigma(p) = 16(j>>2) + 4g + 2((j>>1)&1) + (j&1).
__global__ void v_transpose(const ushort* __restrict__ qkv, ushort* __restrict__ vtg) {
  __shared__ ushort tile[64][72];
  const int bh = blockIdx.y;          // 0..63
  const int kb = blockIdx.x;          // 0..31, 64-key chunk
  const int b = bh >> 4, h = bh & 15;
  const size_t rowbase = (size_t)b * 2048 + kb * 64;
  const int t = threadIdx.x;
  {
    int key = t >> 2, d0 = (t & 3) * 16;
    const ushort* src = qkv + (rowbase + key) * 3072 + h * 192 + 128 + d0;
    *(short8*)&tile[key][d0] = *(const short8*)src;
    *(short8*)&tile[key][d0 + 8] = *(const short8*)(src + 8);
  }
  __syncthreads();
  {
    int d = t >> 2, p0 = (t & 3) * 16;
    ushort out[16];
#pragma unroll
    for (int i = 0; i < 16; ++i) {
      int p = p0 + i;
      int pp = p & 31, j = pp & 7, gg = pp >> 3;
      int sig = 16 * (j >> 2) + 4 * gg + 2 * ((j >> 1) & 1) + (j & 1);
      out[i] = tile[(p & 32) + sig][d];
    }
    ushort* dst = vtg + (size_t)(bh * 64 + d) * 2048 + kb * 64 + p0;
    *(short8*)dst = *(short8*)out;
    *(short8*)(dst + 8) = *(short8*)(out + 8);
  }
}

// ---------------- flash attention (LDS-free, barrier-free) ----------------
__global__ __launch_bounds__(256, 2) void flash_attn(
    const ushort* __restrict__ qkv, const ushort* __restrict__ vtg,
    const float* __restrict__ mask,
    float* __restrict__ values_f, ushort* __restrict__ values_b) {
  const int lane = threadIdx.x & 63;
  const int wv = threadIdx.x >> 6;
  const int c = lane & 15;  // q (S^T cols) / d-row (O^T rows)
  const int g = lane >> 4;  // quarter group
  const int bh = blockIdx.x >> 4;   // bh-major: 16 consecutive blocks share head
  const int qt = blockIdx.x & 15;
  const int b = bh >> 4, h = bh & 15;
  const size_t rowbase = (size_t)b * 2048;
  const int qcol = h * 192;

  // Q b-frags (W_q pre-scaled by 0.125*log2e)
  short8 qf[2][2];
#pragma unroll
  for (int mt = 0; mt < 2; ++mt)
#pragma unroll
    for (int kf = 0; kf < 2; ++kf)
      qf[mt][kf] = *(const short8*)(qkv +
          (rowbase + qt * 128 + wv * 32 + mt * 16 + c) * 3072 + qcol +
          kf * 32 + g * 8);

  f32x4 acc[2][4] = {};
  f32x4 lacc[2] = {};
  float mst[2] = {-3e38f, -3e38f};

  short8 ones8;
#pragma unroll
  for (int e = 0; e < 8; ++e) ones8[e] = (short)0x3f80;

  const ushort* Kb = qkv + rowbase * 3072 + qcol + 64 + g * 8;
  const ushort* Vb = vtg + (size_t)bh * 64 * 2048 + g * 8;
  const float* mrow = mask + (size_t)(qt * 128 + wv * 32 + c) * 2048 + g * 4;

#pragma unroll 1
  for (int kt = 0; kt < 16; ++kt) {
    // ---- K A-frags direct from global ----
    short8 ka[8], kb8[8];
#pragma unroll
    for (int nt = 0; nt < 8; ++nt) {
      const ushort* p = Kb + (size_t)(kt * 128 + nt * 16 + c) * 3072;
      ka[nt] = *(const short8*)(p);
      kb8[nt] = *(const short8*)(p + 32);
    }
    // ---- S^T = K . Q^T ----
    f32x4 sc[2][8];
#pragma unroll
    for (int nt = 0; nt < 8; ++nt) {
      f32x4 zz = {0.f, 0.f, 0.f, 0.f};
      sc[0][nt] = __builtin_amdgcn_mfma_f32_16x16x32_bf16(ka[nt], qf[0][0], zz, 0, 0, 0);
      sc[0][nt] = __builtin_amdgcn_mfma_f32_16x16x32_bf16(kb8[nt], qf[0][1], sc[0][nt], 0, 0, 0);
      sc[1][nt] = __builtin_amdgcn_mfma_f32_16x16x32_bf16(ka[nt], qf[1][0], zz, 0, 0, 0);
      sc[1][nt] = __builtin_amdgcn_mfma_f32_16x16x32_bf16(kb8[nt], qf[1][1], sc[1][nt], 0, 0, 0);
    }
    // ---- V^T A-frags direct from global (pre-permuted) ----
    short8 vfrag[4][4];
#pragma unroll
    for (int dt = 0; dt < 4; ++dt)
#pragma unroll
      for (int kk = 0; kk < 4; ++kk)
        vfrag[dt][kk] = *(const short8*)(Vb + (size_t)(dt * 16 + c) * 2048 +
                                         kt * 128 + kk * 32);

    // ---- online softmax (mask fused via fma(mask, log2e, sc)) ----
    __attribute__((aligned(16))) unsigned int Dw[2][16];
#pragma unroll
    for (int mt = 0; mt < 2; ++mt) {
      f32x4 t4[8];
#pragma unroll
      for (int nt = 0; nt < 8; ++nt) {
        float4 mk = *(const float4*)(mrow + (size_t)mt * 16 * 2048 + kt * 128 + nt * 16);
        t4[nt][0] = fmaf(mk.x, L2E, sc[mt][nt][0]);
        t4[nt][1] = fmaf(mk.y, L2E, sc[mt][nt][1]);
        t4[nt][2] = fmaf(mk.z, L2E, sc[mt][nt][2]);
        t4[nt][3] = fmaf(mk.w, L2E, sc[mt][nt][3]);
      }
      f32x4 vm = t4[0];
#pragma unroll
      for (int nt = 1; nt < 8; ++nt)
#pragma unroll
        for (int r = 0; r < 4; ++r) vm[r] = fmaxf(vm[r], t4[nt][r]);
      float pm = fmaxf(fmaxf(vm[0], vm[1]), fmaxf(vm[2], vm[3]));
      pm = fmaxf(pm, __shfl_xor(pm, 16));
      pm = fmaxf(pm, __shfl_xor(pm, 32));
      float mnew = fmaxf(mst[mt], pm);
      float alpha = exp2f(mst[mt] - mnew);
      mst[mt] = mnew;
#pragma unroll
      for (int nt = 0; nt < 8; ++nt) {
        unsigned int p0 = fbits(exp2f(t4[nt][0] - mnew));
        unsigned int p1 = fbits(exp2f(t4[nt][1] - mnew));
        unsigned int p2 = fbits(exp2f(t4[nt][2] - mnew));
        unsigned int p3 = fbits(exp2f(t4[nt][3] - mnew));
        Dw[mt][nt * 2 + 0] = __builtin_amdgcn_perm(p1, p0, 0x07060302u);
        Dw[mt][nt * 2 + 1] = __builtin_amdgcn_perm(p3, p2, 0x07060302u);
      }
#pragma unroll
      for (int dt = 0; dt < 4; ++dt)
#pragma unroll
        for (int r = 0; r < 4; ++r) acc[mt][dt][r] *= alpha;
      lacc[mt][0] *= alpha;
    }

    // ---- O^T += V^T . P^T ; l via ones-row MFMA ----
    const short8* bu0 = (const short8*)Dw[0];
    const short8* bu1 = (const short8*)Dw[1];
#pragma unroll
    for (int dt = 0; dt < 4; ++dt)
#pragma unroll
      for (int kk = 0; kk < 4; ++kk) {
        acc[0][dt] = __builtin_amdgcn_mfma_f32_16x16x32_bf16(vfrag[dt][kk], bu0[kk], acc[0][dt], 0, 0, 0);
        acc[1][dt] = __builtin_amdgcn_mfma_f32_16x16x32_bf16(vfrag[dt][kk], bu1[kk], acc[1][dt], 0, 0, 0);
      }
#pragma unroll
    for (int kk = 0; kk < 4; ++kk) {
      lacc[0] = __builtin_amdgcn_mfma_f32_16x16x32_bf16(ones8, bu0[kk], lacc[0], 0, 0, 0);
      lacc[1] = __builtin_amdgcn_mfma_f32_16x16x32_bf16(ones8, bu1[kk], lacc[1], 0, 0, 0);
    }
  }

  // ---- epilogue: O^T col=q, rows d = dt*16 + g*4 + r; l from lacc ----
#pragma unroll
  for (int mt = 0; mt < 2; ++mt) {
    float rl = 1.0f / lacc[mt][0];
    size_t qrow = rowbase + qt * 128 + wv * 32 + mt * 16 + c;
#pragma unroll
    for (int dt = 0; dt < 4; ++dt) {
      int d0 = h * 64 + dt * 16 + g * 4;
      float4 o;
      o.x = acc[mt][dt][0] * rl; o.y = acc[mt][dt][1] * rl;
      o.z = acc[mt][dt][2] * rl; o.w = acc[mt][dt][3] * rl;
      *(float4*)(values_f + qrow * 1024 + d0) = o;
      ushort4 ob;
      ob.x = f2b(o.x); ob.y = f2b(o.y); ob.z = f2b(o.z); ob.w = f2b(o.w);
      *(ushort4*)(values_b + qrow * 1024 + d0) = ob;
    }
  }
}

extern "C" void kernel_launch(void* const* d_in, const int* in_sizes, int n_in,
                              void* d_out, int out_size, void* d_ws, size_t ws_size,
                              hipStream_t stream) {
  const float* x    = (const float*)d_in[0];
  const float* mask = (const float*)d_in[1];
  const float* Wqkv = (const float*)d_in[2];
  const float* bqkv = (const float*)d_in[3];
  const float* Wo   = (const float*)d_in[4];
  const float* bo   = (const float*)d_in[5];
  float* out      = (float*)d_out;
  float* values_f = out + 8388608;

  char* ws = (char*)d_ws;
  ushort* xb    = (ushort*)(ws + 0);          // 16 MB x bf16 (dead after gemm1)
  ushort* vtg   = (ushort*)(ws + 0);          // 16 MB V^T (written after gemm1)
  ushort* wqkvt = (ushort*)(ws + 16777216);   // 6 MB   W_qkv^T bf16 (q cols scaled)
  ushort* wot   = (ushort*)(ws + 23068672);   // 2 MB   W_o^T bf16
  ushort* qkv   = (ushort*)(ws + 25165824);   // 48 MB  qkv bf16
  ushort* valb  = (ushort*)(ws + 75497472);   // 16 MB  values bf16
  float*  biass = (float*)(ws + 75497472);    // 12 KB scaled b_qkv (dead before flash)

  cvt_bf16<<<dim3(8192), dim3(256), 0, stream>>>(x, xb, 8388608);
  transpose_cvt<1><<<dim3(48, 16), dim3(256), 0, stream>>>(Wqkv, wqkvt, 1024, 3072);
  transpose_cvt<0><<<dim3(16, 16), dim3(256), 0, stream>>>(Wo, wot, 1024, 1024);
  scale_bias_q<<<dim3(12), dim3(256), 0, stream>>>(bqkv, biass, 3072);
  gemm_bt_bias<0><<<dim3(24, 64), dim3(256), 0, stream>>>(
      xb, wqkvt, biass, (void*)qkv, 8192, 3072, 1024);
  v_transpose<<<dim3(32, 64), dim3(256), 0, stream>>>(qkv, vtg);
  flash_attn<<<dim3(1024), dim3(256), 0, stream>>>(qkv, vtg, mask, values_f, valb);
  gemm_bt_bias<1><<<dim3(8, 64), dim3(256), 0, stream>>>(
      valb, wot, bo, (void*)out, 8192, 1024, 1024);
}

// Round 5
// 558.000 us; speedup vs baseline: 1.1436x; 1.1436x over previous
//
#include <hip/hip_runtime.h>
#include <hip/hip_bf16.h>

// MHA forward: x[4,2048,1024] -> qkv GEMM -> flash attention (transposed
// S^T/O^T, LDS-free, barrier-free; K/V/mask pre-packed into exact MFMA
// fragment order so every flash load is a dense 1KB/wave dwordx4)
// -> out proj. bf16 MFMA 16x16x32, fp32 accumulate.

typedef __attribute__((ext_vector_type(8))) short short8;
typedef __attribute__((ext_vector_type(4))) float f32x4;

#define GLD16(g, l)                                                            \
  __builtin_amdgcn_global_load_lds(                                            \
      (const __attribute__((address_space(1))) unsigned int*)(g),              \
      (__attribute__((address_space(3))) unsigned int*)(l), 16, 0, 0)

#define SCL2E 0.1803368801111204f /* 0.125 * log2(e), folded into W_q */
#define L2E 1.44269504088896340736f

__device__ __forceinline__ unsigned short f2b(float f) {
  union { float f; unsigned int u; } v; v.f = f;
  unsigned int u = v.u;
  return (unsigned short)((u + 0x7fffu + ((u >> 16) & 1u)) >> 16);
}
__device__ __forceinline__ unsigned int fbits(float f) {
  union { float f; unsigned int u; } v; v.f = f; return v.u;
}

// ---------------- elementwise fp32 -> bf16 ----------------
__global__ void cvt_bf16(const float* __restrict__ in, ushort* __restrict__ out, int n) {
  int i = (blockIdx.x * blockDim.x + threadIdx.x) * 4;
  if (i + 3 < n) {
    float4 f = *(const float4*)(in + i);
    ushort4 o;
    o.x = f2b(f.x); o.y = f2b(f.y); o.z = f2b(f.z); o.w = f2b(f.w);
    *(ushort4*)(out + i) = o;
  }
}

// ---------------- bias, q-part scaled by 0.125*log2e ----------------
__global__ void scale_bias_q(const float* __restrict__ b, float* __restrict__ out, int n) {
  int i = blockIdx.x * blockDim.x + threadIdx.x;
  if (i < n) out[i] = b[i] * (((i % 192) < 64) ? SCL2E : 1.0f);
}

// -------- W[K][N] fp32 -> Wt[N][K] bf16; QSCALE: scale q-cols --------
template <int QSCALE>
__global__ void transpose_cvt(const float* __restrict__ W, ushort* __restrict__ Wt,
                              int K, int N) {
  __shared__ float tile[64][65];
  int n0 = blockIdx.x * 64, k0 = blockIdx.y * 64;
  int tx = threadIdx.x & 63, ty = threadIdx.x >> 6;
#pragma unroll
  for (int i = 0; i < 64; i += 4)
    tile[ty + i][tx] = W[(size_t)(k0 + ty + i) * N + n0 + tx];
  __syncthreads();
#pragma unroll
  for (int i = 0; i < 64; i += 4) {
    int n = n0 + ty + i;
    float s = (QSCALE && ((n % 192) < 64)) ? SCL2E : 1.0f;
    Wt[(size_t)n * K + k0 + tx] = f2b(tile[tx][ty + i] * s);
  }
}

// ---------------- GEMM: C[M,N] = A[M,K] @ Bt[N,K]^T + bias ----------------
template <int OUTF32>
__global__ __launch_bounds__(256, 2) void gemm_bt_bias(
    const ushort* __restrict__ A, const ushort* __restrict__ Bt,
    const float* __restrict__ bias, void* __restrict__ Cout,
    int M, int N, int K) {
  __shared__ ushort As[128 * 64];
  __shared__ ushort Bs[128 * 64];
  const int lane = threadIdx.x & 63;
  const int wv = threadIdx.x >> 6;
  const int bm = blockIdx.y, bn = blockIdx.x;
  const int wm = wv >> 1, wn = wv & 1;
  f32x4 acc[4][4] = {};
  const size_t arow0 = (size_t)bm * 128;
  const size_t brow0 = (size_t)bn * 128;

  for (int k0 = 0; k0 < K; k0 += 64) {
    __syncthreads();
#pragma unroll
    for (int i = 0; i < 4; ++i) {
      int r = wv * 32 + i * 8 + (lane >> 3);
      const ushort* ga = A + (arow0 + r) * K + k0 + (lane & 7) * 8;
      GLD16(ga, As + (wv * 32 + i * 8) * 64);
      const ushort* gb = Bt + (brow0 + r) * K + k0 + (lane & 7) * 8;
      GLD16(gb, Bs + (wv * 32 + i * 8) * 64);
    }
    __syncthreads();
    short8 af[2][4], bf[2][4];
#pragma unroll
    for (int kf = 0; kf < 2; ++kf)
#pragma unroll
      for (int t = 0; t < 4; ++t) {
        af[kf][t] = *(const short8*)(As + (wm * 64 + t * 16 + (lane & 15)) * 64 +
                                     kf * 32 + (lane >> 4) * 8);
        bf[kf][t] = *(const short8*)(Bs + (wn * 64 + t * 16 + (lane & 15)) * 64 +
                                     kf * 32 + (lane >> 4) * 8);
      }
#pragma unroll
    for (int kf = 0; kf < 2; ++kf)
#pragma unroll
      for (int mt = 0; mt < 4; ++mt)
#pragma unroll
        for (int nt = 0; nt < 4; ++nt)
          acc[mt][nt] = __builtin_amdgcn_mfma_f32_16x16x32_bf16(
              af[kf][mt], bf[kf][nt], acc[mt][nt], 0, 0, 0);
  }
#pragma unroll
  for (int nt = 0; nt < 4; ++nt) {
    int col = bn * 128 + wn * 64 + nt * 16 + (lane & 15);
    float bv = bias[col];
#pragma unroll
    for (int mt = 0; mt < 4; ++mt) {
      int row0 = bm * 128 + wm * 64 + mt * 16 + (lane >> 4) * 4;
#pragma unroll
      for (int r = 0; r < 4; ++r) {
        float v = acc[mt][nt][r] + bv;
        if (OUTF32)
          ((float*)Cout)[(size_t)(row0 + r) * N + col] = v;
        else
          ((ushort*)Cout)[(size_t)(row0 + r) * N + col] = f2b(v);
      }
    }
  }
}

// ---------------- mask -> fragment order (fp32, bijective permutation) ----
// out[ ((((qt*4+wv)*16 + kt)*2 + mt)*8 + nt)*256 + (g*16+c)*4 + r ]
//   = mask[q = qt*128+wv*32+mt*16+c][k = kt*128+nt*16+g*4+r]
__global__ void mask_reorder(const float* __restrict__ mask, float* __restrict__ out) {
  int idx = blockIdx.x * 256 + threadIdx.x;
  int q = idx >> 9, k4 = idx & 511;
  int k = k4 * 4;
  float4 m = *(const float4*)(mask + (size_t)q * 2048 + k);
  int qt = q >> 7, wvq = (q >> 5) & 3, mt = (q >> 4) & 1, cc = q & 15;
  int kt = k >> 7, nt = (k >> 4) & 7, gg = (k >> 2) & 3;
  int ln = gg * 16 + cc;
  size_t off = ((((size_t)(qt * 4 + wvq) * 16 + kt) * 2 + mt) * 8 + nt) * 256 + ln * 4;
  *(float4*)(out + off) = m;
}

// ---------------- K/V -> fragment order ----------------
// karr[bh][kt][ci=nt*2+kf][lane=(g*16+c)][8] = K[key=nt*16+c][d=kf*32+g*8+j]
// varr[bh][kt][ci=dt*4+kk][lane=(g*16+c)][8] = V[key=kt*128+kk*32+sigma(g,j)][d=dt*16+c]
//   sigma(g,j) = 16*(j>>2) + 4*g + (j&3)   (PV B-frag key order, verified R2/R4)
__global__ __launch_bounds__(256, 2) void kv_reorder(const ushort* __restrict__ qkv,
                                                     ushort* __restrict__ karr,
                                                     ushort* __restrict__ varr) {
  __shared__ ushort Ks[128 * 64];
  __shared__ unsigned int Vdw[64 * 68];  // [d][key-pair dwords], stride 68
  const int bh = blockIdx.x >> 4;
  const int kt = blockIdx.x & 15;
  const int b = bh >> 4, h = bh & 15;
  const size_t rowbase = (size_t)b * 2048 + kt * 128;
  const int qcol = h * 192;
  const int t = threadIdx.x;
  const int lane = t & 63, wv = t >> 6;
  // stage K via GLD16 (coalesced)
#pragma unroll
  for (int i = 0; i < 4; ++i) {
    int rloc = wv * 32 + i * 8;
    const ushort* gk =
        qkv + (rowbase + rloc + (lane >> 3)) * 3072 + qcol + 64 + (lane & 7) * 8;
    GLD16(gk, Ks + rloc * 64);
  }
  // stage V transposed, dword-packed (key pair per thread)
  {
    const int kp = lane, dq = wv;
    const ushort* vg = qkv + (rowbase + kp * 2) * 3072 + qcol + 128 + dq * 16;
    short8 a0 = *(const short8*)(vg);
    short8 a1 = *(const short8*)(vg + 8);
    short8 b0 = *(const short8*)(vg + 3072);
    short8 b1 = *(const short8*)(vg + 3072 + 8);
#pragma unroll
    for (int j = 0; j < 8; ++j)
      Vdw[(dq * 16 + j) * 68 + kp] =
          ((unsigned int)(unsigned short)b0[j] << 16) | (unsigned short)a0[j];
#pragma unroll
    for (int j = 0; j < 8; ++j)
      Vdw[(dq * 16 + 8 + j) * 68 + kp] =
          ((unsigned int)(unsigned short)b1[j] << 16) | (unsigned short)a1[j];
  }
  __syncthreads();
  const size_t obase = (size_t)blockIdx.x * 16 * 512;
  // K out: ci = nt*2+kf
#pragma unroll
  for (int i = 0; i < 4; ++i) {
    int flat = i * 256 + t;
    int ci = flat >> 6, ln = flat & 63;
    int g = ln >> 4, c = ln & 15, nt = ci >> 1, kf = ci & 1;
    short8 v = *(const short8*)(Ks + (nt * 16 + c) * 64 + kf * 32 + g * 8);
    *(short8*)(karr + obase + ci * 512 + ln * 8) = v;
  }
  // V out: ci = dt*4+kk; keys {kk*32+4g..+3} U {kk*32+16+4g..+3}
#pragma unroll
  for (int i = 0; i < 4; ++i) {
    int flat = i * 256 + t;
    int ci = flat >> 6, ln = flat & 63;
    int g = ln >> 4, c = ln & 15, dt = ci >> 2, kk = ci & 3;
    int d = dt * 16 + c;
    unsigned long long lo = *(const unsigned long long*)(Vdw + d * 68 + kk * 16 + 2 * g);
    unsigned long long hi = *(const unsigned long long*)(Vdw + d * 68 + kk * 16 + 8 + 2 * g);
    ushort o8[8];
    *(unsigned long long*)(o8) = lo;
    *(unsigned long long*)(o8 + 4) = hi;
    *(short8*)(varr + obase + ci * 512 + ln * 8) = *(const short8*)o8;
  }
}

// ---------------- flash attention (LDS-free, barrier-free, dense loads) ----
__global__ __launch_bounds__(256, 2) void flash_attn(
    const ushort* __restrict__ qkv, const ushort* __restrict__ karr,
    const ushort* __restrict__ varr, const float* __restrict__ mask_r,
    float* __restrict__ values_f, ushort* __restrict__ values_b) {
  const int lane = threadIdx.x & 63;
  const int wv = threadIdx.x >> 6;
  const int c = lane & 15, g = lane >> 4;
  const int bh = blockIdx.x >> 4;
  const int qt = blockIdx.x & 15;
  const int b = bh >> 4, h = bh & 15;
  const size_t rowbase = (size_t)b * 2048;
  const int qcol = h * 192;

  // Q b-frags (W_q pre-scaled by 0.125*log2e); once per block, scatter OK
  short8 qf[2][2];
#pragma unroll
  for (int mt = 0; mt < 2; ++mt)
#pragma unroll
    for (int kf = 0; kf < 2; ++kf)
      qf[mt][kf] = *(const short8*)(qkv +
          (rowbase + qt * 128 + wv * 32 + mt * 16 + c) * 3072 + qcol +
          kf * 32 + g * 8);

  f32x4 acc[2][4] = {};
  f32x4 lacc[2] = {};
  float mst[2] = {-3e38f, -3e38f};

  short8 ones8;
#pragma unroll
  for (int e = 0; e < 8; ++e) ones8[e] = (short)0x3f80;

  const ushort* Kb = karr + (size_t)bh * 16 * 8192 + lane * 8;
  const ushort* Vb = varr + (size_t)bh * 16 * 8192 + lane * 8;
  const float* Mb = mask_r + (size_t)(qt * 4 + wv) * 16 * 4096 + lane * 4;

#pragma unroll 1
  for (int kt = 0; kt < 16; ++kt) {
    // ---- K A-frags: 16 dense 1KB loads ----
    const ushort* Kt = Kb + kt * 8192;
    short8 kfrag[16];
#pragma unroll
    for (int ci = 0; ci < 16; ++ci) kfrag[ci] = *(const short8*)(Kt + ci * 512);
    // ---- S^T = K . Q^T ----
    f32x4 sc[2][8];
#pragma unroll
    for (int nt = 0; nt < 8; ++nt) {
      f32x4 zz = {0.f, 0.f, 0.f, 0.f};
      sc[0][nt] = __builtin_amdgcn_mfma_f32_16x16x32_bf16(kfrag[nt * 2], qf[0][0], zz, 0, 0, 0);
      sc[0][nt] = __builtin_amdgcn_mfma_f32_16x16x32_bf16(kfrag[nt * 2 + 1], qf[0][1], sc[0][nt], 0, 0, 0);
      sc[1][nt] = __builtin_amdgcn_mfma_f32_16x16x32_bf16(kfrag[nt * 2], qf[1][0], zz, 0, 0, 0);
      sc[1][nt] = __builtin_amdgcn_mfma_f32_16x16x32_bf16(kfrag[nt * 2 + 1], qf[1][1], sc[1][nt], 0, 0, 0);
    }
    // ---- V A-frags: 16 dense 1KB loads (issued early, used after softmax) ----
    const ushort* Vt = Vb + kt * 8192;
    short8 vfrag[16];
#pragma unroll
    for (int ci = 0; ci < 16; ++ci) vfrag[ci] = *(const short8*)(Vt + ci * 512);

    // ---- online softmax (mask in fragment order: dense 1KB loads) ----
    const float* Mt = Mb + kt * 4096;
    __attribute__((aligned(16))) unsigned int Dw[2][16];
#pragma unroll
    for (int mt = 0; mt < 2; ++mt) {
      f32x4 t4[8];
#pragma unroll
      for (int nt = 0; nt < 8; ++nt) {
        float4 mk = *(const float4*)(Mt + (mt * 8 + nt) * 256);
        t4[nt][0] = fmaf(mk.x, L2E, sc[mt][nt][0]);
        t4[nt][1] = fmaf(mk.y, L2E, sc[mt][nt][1]);
        t4[nt][2] = fmaf(mk.z, L2E, sc[mt][nt][2]);
        t4[nt][3] = fmaf(mk.w, L2E, sc[mt][nt][3]);
      }
      f32x4 vm = t4[0];
#pragma unroll
      for (int nt = 1; nt < 8; ++nt)
#pragma unroll
        for (int r = 0; r < 4; ++r) vm[r] = fmaxf(vm[r], t4[nt][r]);
      float pm = fmaxf(fmaxf(vm[0], vm[1]), fmaxf(vm[2], vm[3]));
      pm = fmaxf(pm, __shfl_xor(pm, 16));
      pm = fmaxf(pm, __shfl_xor(pm, 32));
      float mnew = fmaxf(mst[mt], pm);
      float alpha = exp2f(mst[mt] - mnew);
      mst[mt] = mnew;
#pragma unroll
      for (int nt = 0; nt < 8; ++nt) {
        unsigned int p0 = fbits(exp2f(t4[nt][0] - mnew));
        unsigned int p1 = fbits(exp2f(t4[nt][1] - mnew));
        unsigned int p2 = fbits(exp2f(t4[nt][2] - mnew));
        unsigned int p3 = fbits(exp2f(t4[nt][3] - mnew));
        Dw[mt][nt * 2 + 0] = __builtin_amdgcn_perm(p1, p0, 0x07060302u);
        Dw[mt][nt * 2 + 1] = __builtin_amdgcn_perm(p3, p2, 0x07060302u);
      }
#pragma unroll
      for (int dt = 0; dt < 4; ++dt)
#pragma unroll
        for (int r = 0; r < 4; ++r) acc[mt][dt][r] *= alpha;
      lacc[mt][0] *= alpha;
    }

    // ---- O^T += V^T . P^T ; l via ones-row MFMA ----
    const short8* bu0 = (const short8*)Dw[0];
    const short8* bu1 = (const short8*)Dw[1];
#pragma unroll
    for (int dt = 0; dt < 4; ++dt)
#pragma unroll
      for (int kk = 0; kk < 4; ++kk) {
        acc[0][dt] = __builtin_amdgcn_mfma_f32_16x16x32_bf16(vfrag[dt * 4 + kk], bu0[kk], acc[0][dt], 0, 0, 0);
        acc[1][dt] = __builtin_amdgcn_mfma_f32_16x16x32_bf16(vfrag[dt * 4 + kk], bu1[kk], acc[1][dt], 0, 0, 0);
      }
#pragma unroll
    for (int kk = 0; kk < 4; ++kk) {
      lacc[0] = __builtin_amdgcn_mfma_f32_16x16x32_bf16(ones8, bu0[kk], lacc[0], 0, 0, 0);
      lacc[1] = __builtin_amdgcn_mfma_f32_16x16x32_bf16(ones8, bu1[kk], lacc[1], 0, 0, 0);
    }
  }

  // ---- epilogue: O^T col=q, rows d = dt*16 + g*4 + r; l from lacc ----
#pragma unroll
  for (int mt = 0; mt < 2; ++mt) {
    float rl = 1.0f / lacc[mt][0];
    size_t qrow = rowbase + qt * 128 + wv * 32 + mt * 16 + c;
#pragma unroll
    for (int dt = 0; dt < 4; ++dt) {
      int d0 = h * 64 + dt * 16 + g * 4;
      float4 o;
      o.x = acc[mt][dt][0] * rl; o.y = acc[mt][dt][1] * rl;
      o.z = acc[mt][dt][2] * rl; o.w = acc[mt][dt][3] * rl;
      *(float4*)(values_f + qrow * 1024 + d0) = o;
      ushort4 ob;
      ob.x = f2b(o.x); ob.y = f2b(o.y); ob.z = f2b(o.z); ob.w = f2b(o.w);
      *(ushort4*)(values_b + qrow * 1024 + d0) = ob;
    }
  }
}

extern "C" void kernel_launch(void* const* d_in, const int* in_sizes, int n_in,
                              void* d_out, int out_size, void* d_ws, size_t ws_size,
                              hipStream_t stream) {
  const float* x    = (const float*)d_in[0];
  const float* mask = (const float*)d_in[1];
  const float* Wqkv = (const float*)d_in[2];
  const float* bqkv = (const float*)d_in[3];
  const float* Wo   = (const float*)d_in[4];
  const float* bo   = (const float*)d_in[5];
  float* out      = (float*)d_out;
  float* values_f = out + 8388608;

  char* ws = (char*)d_ws;
  ushort* xb    = (ushort*)(ws + 0);           // 16 MB x bf16 (dead after gemm1)
  ushort* karr  = (ushort*)(ws + 0);           // 16 MB K frag-order (after gemm1)
  ushort* wqkvt = (ushort*)(ws + 16777216);    // 6 MB  W_qkv^T bf16 (q cols scaled)
  ushort* wot   = (ushort*)(ws + 23068672);    // 2 MB  W_o^T bf16
  ushort* qkv   = (ushort*)(ws + 25165824);    // 48 MB qkv bf16
  ushort* valb  = (ushort*)(ws + 75497472);    // 16 MB values bf16
  float*  biass = (float*)(ws + 75497472);     // 12 KB scaled b_qkv (dead pre-flash)
  ushort* varr  = (ushort*)(ws + 92274688);    // 16 MB V frag-order
  float*  mrord = (float*)(ws + 109051904);    // 16 MB mask frag-order (fp32)

  cvt_bf16<<<dim3(8192), dim3(256), 0, stream>>>(x, xb, 8388608);
  transpose_cvt<1><<<dim3(48, 16), dim3(256), 0, stream>>>(Wqkv, wqkvt, 1024, 3072);
  transpose_cvt<0><<<dim3(16, 16), dim3(256), 0, stream>>>(Wo, wot, 1024, 1024);
  scale_bias_q<<<dim3(12), dim3(256), 0, stream>>>(bqkv, biass, 3072);
  mask_reorder<<<dim3(4096), dim3(256), 0, stream>>>(mask, mrord);
  gemm_bt_bias<0><<<dim3(24, 64), dim3(256), 0, stream>>>(
      xb, wqkvt, biass, (void*)qkv, 8192, 3072, 1024);
  kv_reorder<<<dim3(1024), dim3(256), 0, stream>>>(qkv, karr, varr);
  flash_attn<<<dim3(1024), dim3(256), 0, stream>>>(qkv, karr, varr, mrord,
                                                   values_f, valb);
  gemm_bt_bias<1><<<dim3(8, 64), dim3(256), 0, stream>>>(
      valb, wot, bo, (void*)out, 8192, 1024, 1024);
}